// Round 9
// baseline (250.777 us; speedup 1.0000x reference)
//
#include <hip/hip_runtime.h>

#define NPTS 8192
#define DIM 64
#define BATCH 2
#define KOUT 17
#define QCAP 40     // queue capacity per (row, seg)
#define THRANK 21   // theta = 22nd smallest of the 64-subset

typedef float f32x4 __attribute__((ext_vector_type(4)));
typedef short short8 __attribute__((ext_vector_type(8)));
typedef unsigned int uint4v __attribute__((ext_vector_type(4)));

// ---------- prep: permuted hi/lo bf16 (phl), contiguous f32 (pct), 0.5*|x|^2 ----------
__global__ __launch_bounds__(256)
void prep_kernel(const float* __restrict__ pc, ushort* __restrict__ phl,
                 float* __restrict__ pct, float* __restrict__ sq) {
  __shared__ double psum[256];
  int t = threadIdx.x;
  int u = t >> 5;           // 0..7  (dims u*8 .. u*8+7)
  int p = t & 31;           // 0..31 (point within block)
  int i = blockIdx.x * 32 + p;   // 0..16383
  int b = i >> 13, n = i & (NPTS - 1);
  const float* g = pc + (size_t)b * DIM * NPTS + n;

  float x[8];
  short8 hv, lv;
  double s = 0.0;
  #pragma unroll
  for (int e = 0; e < 8; ++e) {
    x[e] = g[(size_t)(u * 8 + e) * NPTS];
    s += (double)x[e] * (double)x[e];
    unsigned uu = __float_as_uint(x[e]);
    unsigned r = uu + (0x7fffu + ((uu >> 16) & 1));
    unsigned hi = r >> 16;                       // bf16 RNE
    float xl = x[e] - __uint_as_float(hi << 16);
    unsigned ul = __float_as_uint(xl);
    unsigned rl = ul + (0x7fffu + ((ul >> 16) & 1));
    hv[e] = (short)(hi & 0xffffu);
    lv[e] = (short)((rl >> 16) & 0xffffu);
  }
  int slot = u ^ (n & 7);
  ushort* ph = phl + (size_t)i * 128;
  *(short8*)(ph + slot * 8) = hv;
  *(short8*)(ph + 64 + slot * 8) = lv;
  f32x4 v0 = {x[0], x[1], x[2], x[3]}, v1 = {x[4], x[5], x[6], x[7]};
  *(f32x4*)(pct + (size_t)i * 64 + u * 8) = v0;
  *(f32x4*)(pct + (size_t)i * 64 + u * 8 + 4) = v1;

  psum[u * 32 + p] = s;
  __syncthreads();
  if (t < 32) {
    double acc = 0.0;
    #pragma unroll
    for (int uu = 0; uu < 8; ++uu) acc += psum[uu * 32 + t];
    sq[blockIdx.x * 32 + t] = (float)(0.5 * acc);   // HALF |x|^2
  }
}

// ---------- two-pass MFMA distance + theta-filter, B direct from global (no LDS staging) ----------
// 1024 blocks x 256 threads; block = (b, seg, rowgroup): 32 rows x 4096 cols (32 tiles of 128).
// wave w covers cols w*32..w*32+31 (2 cf), ALL 32 rows (2 row-groups of 16).
// key(row,col) = 0.5*|col|^2 - <row,col>.  B-fragments gathered from L2-resident phl.
__global__ __launch_bounds__(256, 4)
void knn_kernel(const ushort* __restrict__ phl, const float* __restrict__ sq,
                ushort* __restrict__ cand) {
  __shared__ float KT[32 * 128];   // 16 KB
  __shared__ float KT2[32 * 64];   // 8 KB
  __shared__ float TH[32];
  __shared__ int CNT[32];
  __shared__ ushort QU[32][QCAP];

  int t = threadIdx.x;
  int lane = t & 63;
  int w = t >> 6;
  int b = blockIdx.x >> 9;
  int seg = (blockIdx.x >> 8) & 1;
  int row0 = (blockIdx.x & 255) * 32;
  const ushort* pb = phl + (size_t)b * NPTS * 128;
  const float* sqb = sq + b * NPTS;

  int c15 = lane & 15, l4 = lane >> 4;
  int ccol = w * 32;
  int sw8 = c15 & 7;
  int so0 = (l4 ^ sw8) * 8;          // kk=0 slot offset (ushorts)
  int so1 = ((4 + l4) ^ sw8) * 8;    // kk=1

  // per-lane B base pointers for the two cf columns
  const ushort* pb0 = pb + (size_t)(ccol + c15) * 128;
  const ushort* pb1 = pb + (size_t)(ccol + 16 + c15) * 128;

  // A fragments [hl][kk][rg], rows row0 + rg*16 + c15, sign-flipped (exact)
  short8 a[2][2][2];
  #pragma unroll
  for (int rg = 0; rg < 2; ++rg) {
    int n = row0 + rg * 16 + c15;
    const ushort* pr = pb + (size_t)n * 128;
    #pragma unroll
    for (int hl = 0; hl < 2; ++hl)
      #pragma unroll
      for (int kk = 0; kk < 2; ++kk) {
        int slot = (kk * 4 + l4) ^ (n & 7);
        short8 v = *(const short8*)(pr + hl * 64 + slot * 8);
        uint4v uv = *(uint4v*)&v;
        uv ^= 0x80008000u;
        a[hl][kk][rg] = *(short8*)&uv;
      }
  }

  // ================= PASS A: per-lane top-2 per owned row (8 rows/lane) =================
  float k1[2][4], k2[2][4];
  #pragma unroll
  for (int rg = 0; rg < 2; ++rg)
    #pragma unroll
    for (int r = 0; r < 4; ++r) { k1[rg][r] = __builtin_inff(); k2[rg][r] = __builtin_inff(); }

  for (int tile = 0; tile < 32; ++tile) {
    int n0 = (seg * 32 + tile) * 128;
    size_t off = (size_t)n0 * 128;
    float sqv0 = sqb[n0 + ccol + c15];
    float sqv1 = sqb[n0 + ccol + 16 + c15];

    #pragma unroll
    for (int cf = 0; cf < 2; ++cf) {
      const ushort* q = (cf ? pb1 : pb0) + off;
      float sv = cf ? sqv1 : sqv0;
      short8 bh0 = *(const short8*)(q + so0);
      short8 bl0 = *(const short8*)(q + 64 + so0);
      short8 bh1 = *(const short8*)(q + so1);
      short8 bl1 = *(const short8*)(q + 64 + so1);
      f32x4 c0 = {sv, sv, sv, sv};
      f32x4 c1 = c0;
      c0 = __builtin_amdgcn_mfma_f32_16x16x32_bf16(a[0][0][0], bh0, c0, 0, 0, 0);
      c1 = __builtin_amdgcn_mfma_f32_16x16x32_bf16(a[0][0][1], bh0, c1, 0, 0, 0);
      c0 = __builtin_amdgcn_mfma_f32_16x16x32_bf16(a[0][0][0], bl0, c0, 0, 0, 0);
      c1 = __builtin_amdgcn_mfma_f32_16x16x32_bf16(a[0][0][1], bl0, c1, 0, 0, 0);
      c0 = __builtin_amdgcn_mfma_f32_16x16x32_bf16(a[1][0][0], bh0, c0, 0, 0, 0);
      c1 = __builtin_amdgcn_mfma_f32_16x16x32_bf16(a[1][0][1], bh0, c1, 0, 0, 0);
      c0 = __builtin_amdgcn_mfma_f32_16x16x32_bf16(a[0][1][0], bh1, c0, 0, 0, 0);
      c1 = __builtin_amdgcn_mfma_f32_16x16x32_bf16(a[0][1][1], bh1, c1, 0, 0, 0);
      c0 = __builtin_amdgcn_mfma_f32_16x16x32_bf16(a[0][1][0], bl1, c0, 0, 0, 0);
      c1 = __builtin_amdgcn_mfma_f32_16x16x32_bf16(a[0][1][1], bl1, c1, 0, 0, 0);
      c0 = __builtin_amdgcn_mfma_f32_16x16x32_bf16(a[1][1][0], bh1, c0, 0, 0, 0);
      c1 = __builtin_amdgcn_mfma_f32_16x16x32_bf16(a[1][1][1], bh1, c1, 0, 0, 0);
      #pragma unroll
      for (int r = 0; r < 4; ++r) {
        k2[0][r] = __builtin_amdgcn_fmed3f(c0[r], k1[0][r], k2[0][r]);
        k1[0][r] = fminf(c0[r], k1[0][r]);
        k2[1][r] = __builtin_amdgcn_fmed3f(c1[r], k1[1][r], k2[1][r]);
        k1[1][r] = fminf(c1[r], k1[1][r]);
      }
    }
  }

  // ================= subset: KT[32][128], then pair-merge to KT2[32][64] =================
  __syncthreads();
  #pragma unroll
  for (int rg = 0; rg < 2; ++rg)
    #pragma unroll
    for (int r = 0; r < 4; ++r) {
      int row = rg * 16 + l4 * 4 + r;
      KT[row * 128 + (w * 16 + c15) * 2] = k1[rg][r];
      KT[row * 128 + (w * 16 + c15) * 2 + 1] = k2[rg][r];
    }
  __syncthreads();
  #pragma unroll
  for (int it = 0; it < 4; ++it) {
    int idx = t + it * 256;               // 0..1023
    int row = idx >> 5, j = idx & 31;
    float a1 = KT[row * 128 + j * 2], a2 = KT[row * 128 + j * 2 + 1];
    float b1 = KT[row * 128 + 64 + j * 2], b2 = KT[row * 128 + 64 + j * 2 + 1];
    KT2[row * 64 + j * 2] = fminf(a1, b1);
    KT2[row * 64 + j * 2 + 1] = fminf(fmaxf(a1, b1), fminf(a2, b2));
  }
  __syncthreads();

  // ================= theta per row = 22nd smallest of 64-subset =================
  {
    int row = t >> 3;
    int j0 = (t & 7) * 8;
    const f32x4* vr4 = (const f32x4*)(KT2 + row * 64);
    float vj[8];
    *(f32x4*)vj = vr4[(t & 7) * 2];
    *(f32x4*)(vj + 4) = vr4[(t & 7) * 2 + 1];
    int rank[8];
    #pragma unroll
    for (int jj = 0; jj < 8; ++jj) rank[jj] = 0;
    for (int m4 = 0; m4 < 16; ++m4) {
      f32x4 vm = vr4[m4];
      #pragma unroll
      for (int e = 0; e < 4; ++e) {
        int m = m4 * 4 + e;
        float ve = vm[e];
        #pragma unroll
        for (int jj = 0; jj < 8; ++jj)
          rank[jj] += (ve < vj[jj] || (ve == vj[jj] && m < j0 + jj)) ? 1 : 0;
      }
    }
    #pragma unroll
    for (int jj = 0; jj < 8; ++jj)
      if (rank[jj] == THRANK) TH[row] = vj[jj];
    if (t < 32) CNT[t] = 0;
  }
  __syncthreads();
  float th[2][4];
  #pragma unroll
  for (int rg = 0; rg < 2; ++rg)
    #pragma unroll
    for (int r = 0; r < 4; ++r) th[rg][r] = TH[rg * 16 + l4 * 4 + r];

  // ================= PASS B: recompute + collect key<=theta =================
  for (int tile = 0; tile < 32; ++tile) {
    int n0 = (seg * 32 + tile) * 128;
    size_t off = (size_t)n0 * 128;
    float sqv0 = sqb[n0 + ccol + c15];
    float sqv1 = sqb[n0 + ccol + 16 + c15];

    #pragma unroll
    for (int cf = 0; cf < 2; ++cf) {
      const ushort* q = (cf ? pb1 : pb0) + off;
      float sv = cf ? sqv1 : sqv0;
      int p = ccol + cf * 16 + c15;
      short8 bh0 = *(const short8*)(q + so0);
      short8 bl0 = *(const short8*)(q + 64 + so0);
      short8 bh1 = *(const short8*)(q + so1);
      short8 bl1 = *(const short8*)(q + 64 + so1);
      f32x4 c0 = {sv, sv, sv, sv};
      f32x4 c1 = c0;
      c0 = __builtin_amdgcn_mfma_f32_16x16x32_bf16(a[0][0][0], bh0, c0, 0, 0, 0);
      c1 = __builtin_amdgcn_mfma_f32_16x16x32_bf16(a[0][0][1], bh0, c1, 0, 0, 0);
      c0 = __builtin_amdgcn_mfma_f32_16x16x32_bf16(a[0][0][0], bl0, c0, 0, 0, 0);
      c1 = __builtin_amdgcn_mfma_f32_16x16x32_bf16(a[0][0][1], bl0, c1, 0, 0, 0);
      c0 = __builtin_amdgcn_mfma_f32_16x16x32_bf16(a[1][0][0], bh0, c0, 0, 0, 0);
      c1 = __builtin_amdgcn_mfma_f32_16x16x32_bf16(a[1][0][1], bh0, c1, 0, 0, 0);
      c0 = __builtin_amdgcn_mfma_f32_16x16x32_bf16(a[0][1][0], bh1, c0, 0, 0, 0);
      c1 = __builtin_amdgcn_mfma_f32_16x16x32_bf16(a[0][1][1], bh1, c1, 0, 0, 0);
      c0 = __builtin_amdgcn_mfma_f32_16x16x32_bf16(a[0][1][0], bl1, c0, 0, 0, 0);
      c1 = __builtin_amdgcn_mfma_f32_16x16x32_bf16(a[0][1][1], bl1, c1, 0, 0, 0);
      c0 = __builtin_amdgcn_mfma_f32_16x16x32_bf16(a[1][1][0], bh1, c0, 0, 0, 0);
      c1 = __builtin_amdgcn_mfma_f32_16x16x32_bf16(a[1][1][1], bh1, c1, 0, 0, 0);
      #pragma unroll
      for (int r = 0; r < 4; ++r) {
        if (c0[r] <= th[0][r]) {
          int row = l4 * 4 + r;
          int pos = atomicAdd(&CNT[row], 1);
          if (pos < QCAP) QU[row][pos] = (ushort)(n0 + p);
        }
        if (c1[r] <= th[1][r]) {
          int row = 16 + l4 * 4 + r;
          int pos = atomicAdd(&CNT[row], 1);
          if (pos < QCAP) QU[row][pos] = (ushort)(n0 + p);
        }
      }
    }
  }

  // ================= pad + dump queues =================
  __syncthreads();
  for (int i = t; i < 32 * QCAP; i += 256) {
    int row = i / QCAP, s2 = i % QCAP;
    int c2 = CNT[row]; if (c2 > QCAP) c2 = QCAP;
    ushort v = (s2 < c2) ? QU[row][s2] : (ushort)0xFFFFu;
    cand[((size_t)(b * NPTS + row0 + row) * 2 + seg) * QCAP + s2] = v;
  }
}

// ---------- exact f64 re-rank of up to 80 candidates, wave per point ----------
__global__ void refine_kernel(const float* __restrict__ pct, const ushort* __restrict__ cand,
                              int* __restrict__ knn, float* __restrict__ idxf) {
  int gw = (blockIdx.x * 256 + threadIdx.x) >> 6;  // 0..16383
  int lane = threadIdx.x & 63;
  int b = gw >> 13, n = gw & (NPTS - 1);
  const float* pcb = pct + (size_t)b * NPTS * 64;
  const ushort* cb = cand + (size_t)gw * (2 * QCAP);
  const float* qp = pcb + (size_t)n * 64;

  unsigned ciA = cb[lane];
  unsigned ciB = (lane < 2 * QCAP - 64) ? (unsigned)cb[64 + lane] : 0xFFFFu;
  double dA = __builtin_inf(), dB = __builtin_inf();
  if (ciA != 0xFFFFu) {
    const float* cp = pcb + (size_t)ciA * 64;
    double s = 0.0;
    #pragma unroll
    for (int u = 0; u < 16; ++u) {
      f32x4 cv = *(const f32x4*)(cp + u * 4);
      f32x4 qv = *(const f32x4*)(qp + u * 4);
      #pragma unroll
      for (int e = 0; e < 4; ++e) {
        double diff = (double)cv[e] - (double)qv[e];
        s = fma(diff, diff, s);
      }
    }
    dA = s;
  }
  if (ciB != 0xFFFFu) {
    const float* cp = pcb + (size_t)ciB * 64;
    double s = 0.0;
    #pragma unroll
    for (int u = 0; u < 16; ++u) {
      f32x4 cv = *(const f32x4*)(cp + u * 4);
      f32x4 qv = *(const f32x4*)(qp + u * 4);
      #pragma unroll
      for (int e = 0; e < 4; ++e) {
        double diff = (double)cv[e] - (double)qv[e];
        s = fma(diff, diff, s);
      }
    }
    dB = s;
  }

  int rA = 0, rB = 0;
  for (int j = 0; j < 64; ++j) {
    double dk = __shfl(dA, j);
    unsigned ik = (unsigned)__shfl((int)ciA, j);
    rA += ((dk < dA) || (dk == dA && ik < ciA)) ? 1 : 0;
    rB += ((dk < dB) || (dk == dB && ik < ciB)) ? 1 : 0;
  }
  for (int j = 0; j < 2 * QCAP - 64; ++j) {
    double dk = __shfl(dB, j);
    unsigned ik = (unsigned)__shfl((int)ciB, j);
    rA += ((dk < dA) || (dk == dA && ik < ciA)) ? 1 : 0;
    rB += ((dk < dB) || (dk == dB && ik < ciB)) ? 1 : 0;
  }
  if (ciA != 0xFFFFu && rA < KOUT) {
    size_t o = ((size_t)b * KOUT + rA) * NPTS + n;
    knn[o] = (int)ciA;
    idxf[o] = (float)ciA;
  }
  if (lane < 2 * QCAP - 64 && ciB != 0xFFFFu && rB < KOUT) {
    size_t o = ((size_t)b * KOUT + rB) * NPTS + n;
    knn[o] = (int)ciB;
    idxf[o] = (float)ciB;
  }
}

// ---------- edge features: out [B][128][17][N]; block = (n-chunk, b*64+c), k-loop inside ----------
__global__ __launch_bounds__(256)
void edge_kernel(const float* __restrict__ pc, const int* __restrict__ knn,
                 float* __restrict__ out) {
  int n = blockIdx.x * 256 + threadIdx.x;
  int z = blockIdx.y;
  int b = z >> 6, c = z & 63;
  const float* row = pc + ((size_t)b * DIM + c) * NPTS;
  float central = row[n];
  size_t base = (((size_t)b * 2 * DIM + c) * KOUT) * NPTS + n;
  const int* kb = knn + (size_t)b * KOUT * NPTS + n;
  #pragma unroll
  for (int k = 0; k < KOUT; ++k) {
    int nb = kb[(size_t)k * NPTS];
    float nbrv = row[nb];
    out[base + (size_t)k * NPTS] = central;
    out[base + (size_t)(DIM * KOUT + k) * NPTS] = nbrv - central;
  }
}

extern "C" void kernel_launch(void* const* d_in, const int* in_sizes, int n_in,
                              void* d_out, int out_size, void* d_ws, size_t ws_size,
                              hipStream_t stream) {
  const float* pc = (const float*)d_in[0];
  float* out = (float*)d_out;
  char* ws = (char*)d_ws;
  ushort* phl = (ushort*)ws;                                     // 4 MB
  float* pct  = (float*)(ws + (size_t)4 * 1024 * 1024);          // 4 MB
  float* sq   = (float*)(ws + (size_t)8 * 1024 * 1024);          // 64 KB
  ushort* cand = (ushort*)(ws + (size_t)8 * 1024 * 1024 + 65536);
  int* knn    = (int*)(ws + (size_t)8 * 1024 * 1024 + 65536 + (size_t)16384 * 2 * QCAP * 2);

  float* idxf = out + (size_t)BATCH * 2 * DIM * KOUT * NPTS;

  prep_kernel<<<512, 256, 0, stream>>>(pc, phl, pct, sq);
  knn_kernel<<<1024, 256, 0, stream>>>(phl, sq, cand);
  refine_kernel<<<4096, 256, 0, stream>>>(pct, cand, knn, idxf);
  edge_kernel<<<dim3(NPTS / 256, BATCH * DIM), 256, 0, stream>>>(pc, knn, out);
}